// Round 11
// baseline (97.565 us; speedup 1.0000x reference)
//
#include <hip/hip_runtime.h>

// Capsule routing, MI355X. B=2048, I=64, O=32, DI=DO=16, 3 iters.
// R10 post-mortem: transposed-x b128 reads conflicted 15.7M cycles because
// lanes L and L+32 are co-scheduled on the LDS pipe and, with 80 B row
// stride, land on the SAME bank-quad (32*stride = 0 mod 128 B always, and
// the old rotation ignored lane bit 5). R11 fix: e-quad rotation
//   rot(i) = ((i>>3) + (i>>5)) & 3
// so all pairs (L,L+8/16/32) land on different quads; intra-8-lane-group
// distinctness (20h mod 32 quad permutation) and 2-way-free staging writes
// preserved; write/read rotation cancels so semantics are unchanged.
// Everything else identical to R10 (numerically verified):
// Block = 512 thr (8 waves), one o, 32 b in 4 sub-rounds of 8.
// LDS 72 KB dynamic: p 32 KB + x_t 40 KB -> 2 blocks/CU.
// A-phase: lane=i, wave w owns d-pair {2w,2w+1}; wq=32 regs; x via 4
//   ds_read_b128 per bb from transposed [b][i][20] tile.
// B-phase: wave=bp, lane=(qB,dB); p[16] via 4 swizzled b128; i-combine
//   shfl_xor(16,32); squash-norm shfl_xor(1,2,4,8); 4-chain tree reductions.
// T14 split staging; straight-line, constant-indexed arrays (R7 lesson);
// builtin exp2/rcp/sqrt (no overflow: |arg|<~95); no min-wave forcing.

#define THREADS 512

__global__ __launch_bounds__(THREADS) void routing_kernel(
    const float* __restrict__ x,    // (B, DI, I) = (2048,16,64)
    const float* __restrict__ rw,   // (O, I, DO, DI) = (32,64,16,16)
    const float* __restrict__ ns,   // same
    float* __restrict__ out)        // (1, O, B, DO)
{
    extern __shared__ float lds[];  // 73728 B: [0,8192) p; [8192,18432) x_t
    float* xlds = lds + 8192;       // [bb][i][20] padded, e-quad swizzled

    const int tid  = threadIdx.x;
    const int w    = tid >> 6;      // wave 0..7
    const int lane = tid & 63;      // = i in A-phase

    const int o  = blockIdx.x >> 6;   // o-major: 64 consecutive blocks share W
    const int bc = blockIdx.x & 63;   // 32-b chunk
    const int bbase = bc * 32;

    // ---- W+noise fragment: lane=i, d in {2w, 2w+1} (32 VGPR) ----
    float wq0[16], wq1[16];
    {
        const int base = (o * 64 + lane) * 256 + w * 32;
        #pragma unroll
        for (int eq = 0; eq < 4; ++eq) {
            const float4 a0 = *reinterpret_cast<const float4*>(rw + base + eq * 4);
            const float4 n0 = *reinterpret_cast<const float4*>(ns + base + eq * 4);
            wq0[4*eq+0] = a0.x + n0.x;  wq0[4*eq+1] = a0.y + n0.y;
            wq0[4*eq+2] = a0.z + n0.z;  wq0[4*eq+3] = a0.w + n0.w;
            const float4 a1 = *reinterpret_cast<const float4*>(rw + base + 16 + eq * 4);
            const float4 n1 = *reinterpret_cast<const float4*>(ns + base + 16 + eq * 4);
            wq1[4*eq+0] = a1.x + n1.x;  wq1[4*eq+1] = a1.y + n1.y;
            wq1[4*eq+2] = a1.z + n1.z;  wq1[4*eq+3] = a1.w + n1.w;
        }
    }

    // ---- precomputed LDS addresses ----
    // p writes (A-phase), rows of 64, XOR-swizzled 16B slots (conflict-free)
    const int d0 = 2 * w, d1 = 2 * w + 1;
    float* pw0 = lds + d0 * 64 + ((((lane >> 2) ^ (d0 & 7)) << 2) | (lane & 3));
    float* pw1 = lds + d1 * 64 + ((((lane >> 2) ^ (d1 & 7)) << 2) | (lane & 3));

    // p reads (B-phase)
    const int qB  = lane >> 4;      // i-quarter 0..3
    const int dB  = lane & 15;
    const int swz = dB & 7;
    const float4* prbase = reinterpret_cast<const float4*>(lds) + (w * 16 + dB) * 16;
    const float4* pr0 = prbase + ((4 * qB + 0) ^ swz);
    const float4* pr1 = prbase + ((4 * qB + 1) ^ swz);
    const float4* pr2 = prbase + ((4 * qB + 2) ^ swz);
    const float4* pr3 = prbase + ((4 * qB + 3) ^ swz);

    // x_t reads (A-phase): lane = i = row; slot_j = (4j + 4*rot(i)) & 15
    // rot(i) = ((i>>3) + (i>>5)) & 3  -- bit5 term breaks (L,L+32) pairing
    const int rrd = (((lane >> 3) + (lane >> 5)) & 3) << 2;
    const float* xr0 = xlds + lane * 20 + ((0  + rrd) & 15);
    const float* xr1 = xlds + lane * 20 + ((4  + rrd) & 15);
    const float* xr2 = xlds + lane * 20 + ((8  + rrd) & 15);
    const float* xr3 = xlds + lane * 20 + ((12 + rrd) & 15);

    // x_t writes (staging): thread holds (b=w, e=4k+ih, i=4il+m)
    // rows 4il+m: row>>3 = il>>1, row>>5 = il>>3 (same for m=0..3)
    const int il = lane & 15, ih = lane >> 4;
    const int rwz = (((il >> 1) + (il >> 3)) & 3) << 2;
    float* xw0 = xlds + w * 1280 + il * 80 + ((0  + ih + rwz) & 15);
    float* xw1 = xlds + w * 1280 + il * 80 + ((4  + ih + rwz) & 15);
    float* xw2 = xlds + w * 1280 + il * 80 + ((8  + ih + rwz) & 15);
    float* xw3 = xlds + w * 1280 + il * 80 + ((12 + ih + rwz) & 15);

    const float4* xsrc0 = reinterpret_cast<const float4*>(x) + bbase * 256
                        + (w * 256 + lane);

    const int outbase = (o * 2048 + bbase + w) * 16 + dB;

    // ---- prologue: stage x-tile 0 (transposed+swizzled) ----
    float4 xb0 = xsrc0[0];
    float4 xb1 = xsrc0[64];
    float4 xb2 = xsrc0[128];
    float4 xb3 = xsrc0[192];
    xw0[0] = xb0.x;  xw0[20] = xb0.y;  xw0[40] = xb0.z;  xw0[60] = xb0.w;
    xw1[0] = xb1.x;  xw1[20] = xb1.y;  xw1[40] = xb1.z;  xw1[60] = xb1.w;
    xw2[0] = xb2.x;  xw2[20] = xb2.y;  xw2[40] = xb2.z;  xw2[60] = xb2.w;
    xw3[0] = xb3.x;  xw3[20] = xb3.y;  xw3[40] = xb3.z;  xw3[60] = xb3.w;
    __syncthreads();                // x-tile 0 ready

    #pragma unroll
    for (int s = 0; s < 4; ++s) {
        // ---- A-phase: x_t -> p (8 b's, 4 b128 reads each) ----
        #pragma unroll
        for (int bb = 0; bb < 8; ++bb) {
            const float4 v0 = *reinterpret_cast<const float4*>(xr0 + bb * 1280);
            const float4 v1 = *reinterpret_cast<const float4*>(xr1 + bb * 1280);
            const float4 v2 = *reinterpret_cast<const float4*>(xr2 + bb * 1280);
            const float4 v3 = *reinterpret_cast<const float4*>(xr3 + bb * 1280);
            float a0 = 0.f, a1 = 0.f;
            a0 = fmaf(wq0[0],  v0.x, a0);  a1 = fmaf(wq1[0],  v0.x, a1);
            a0 = fmaf(wq0[1],  v0.y, a0);  a1 = fmaf(wq1[1],  v0.y, a1);
            a0 = fmaf(wq0[2],  v0.z, a0);  a1 = fmaf(wq1[2],  v0.z, a1);
            a0 = fmaf(wq0[3],  v0.w, a0);  a1 = fmaf(wq1[3],  v0.w, a1);
            a0 = fmaf(wq0[4],  v1.x, a0);  a1 = fmaf(wq1[4],  v1.x, a1);
            a0 = fmaf(wq0[5],  v1.y, a0);  a1 = fmaf(wq1[5],  v1.y, a1);
            a0 = fmaf(wq0[6],  v1.z, a0);  a1 = fmaf(wq1[6],  v1.z, a1);
            a0 = fmaf(wq0[7],  v1.w, a0);  a1 = fmaf(wq1[7],  v1.w, a1);
            a0 = fmaf(wq0[8],  v2.x, a0);  a1 = fmaf(wq1[8],  v2.x, a1);
            a0 = fmaf(wq0[9],  v2.y, a0);  a1 = fmaf(wq1[9],  v2.y, a1);
            a0 = fmaf(wq0[10], v2.z, a0);  a1 = fmaf(wq1[10], v2.z, a1);
            a0 = fmaf(wq0[11], v2.w, a0);  a1 = fmaf(wq1[11], v2.w, a1);
            a0 = fmaf(wq0[12], v3.x, a0);  a1 = fmaf(wq1[12], v3.x, a1);
            a0 = fmaf(wq0[13], v3.y, a0);  a1 = fmaf(wq1[13], v3.y, a1);
            a0 = fmaf(wq0[14], v3.z, a0);  a1 = fmaf(wq1[14], v3.z, a1);
            a0 = fmaf(wq0[15], v3.w, a0);  a1 = fmaf(wq1[15], v3.w, a1);
            pw0[bb * 1024] = a0;
            pw1[bb * 1024] = a1;
        }
        __syncthreads();            // p ready; x_t free

        // ---- B-read: p[16] (i = qB*16 + 4jj + m) ----
        float p[16];
        {
            const float4 v0 = *pr0, v1 = *pr1, v2 = *pr2, v3 = *pr3;
            p[0]=v0.x; p[1]=v0.y; p[2]=v0.z; p[3]=v0.w;
            p[4]=v1.x; p[5]=v1.y; p[6]=v1.z; p[7]=v1.w;
            p[8]=v2.x; p[9]=v2.y; p[10]=v2.z; p[11]=v2.w;
            p[12]=v3.x; p[13]=v3.y; p[14]=v3.z; p[15]=v3.w;
        }

        // ---- T14 issue-early: next x-tile global loads ----
        if (s < 3) {
            const float4* xsrc = xsrc0 + (s + 1) * 2048;
            xb0 = xsrc[0];  xb1 = xsrc[64];  xb2 = xsrc[128];  xb3 = xsrc[192];
        }

        // ---- routing iterations ----
        float t0 = (p[0]+p[1]) + (p[2]+p[3]);
        float t1 = (p[4]+p[5]) + (p[6]+p[7]);
        float t2 = (p[8]+p[9]) + (p[10]+p[11]);
        float t3 = (p[12]+p[13]) + (p[14]+p[15]);
        float part = (t0 + t1) + (t2 + t3);
        part += __shfl_xor(part, 16);
        part += __shfl_xor(part, 32);
        float sv = part * (1.0f / 64.0f);

        float sn = sv * sv;         // squash norm over d (16-lane groups)
        sn += __shfl_xor(sn, 1); sn += __shfl_xor(sn, 2);
        sn += __shfl_xor(sn, 4); sn += __shfl_xor(sn, 8);
        float factor = __builtin_amdgcn_sqrtf(sn)
                     * __builtin_amdgcn_rcpf(1.0f + sn);
        float Vsum = sv * factor;

        #pragma unroll
        for (int it = 0; it < 2; ++it) {
            const float c = Vsum * 1.44269504089f;      // log2(e)
            float e0, e1, e2, e3;
            float dd0, dd1, dd2, dd3, nn0, nn1, nn2, nn3;
            e0 = __builtin_amdgcn_exp2f(p[0] * c);
            e1 = __builtin_amdgcn_exp2f(p[1] * c);
            e2 = __builtin_amdgcn_exp2f(p[2] * c);
            e3 = __builtin_amdgcn_exp2f(p[3] * c);
            dd0 = e0; dd1 = e1; dd2 = e2; dd3 = e3;
            nn0 = e0 * p[0]; nn1 = e1 * p[1]; nn2 = e2 * p[2]; nn3 = e3 * p[3];
            e0 = __builtin_amdgcn_exp2f(p[4] * c);
            e1 = __builtin_amdgcn_exp2f(p[5] * c);
            e2 = __builtin_amdgcn_exp2f(p[6] * c);
            e3 = __builtin_amdgcn_exp2f(p[7] * c);
            dd0 += e0; dd1 += e1; dd2 += e2; dd3 += e3;
            nn0 = fmaf(e0, p[4], nn0); nn1 = fmaf(e1, p[5], nn1);
            nn2 = fmaf(e2, p[6], nn2); nn3 = fmaf(e3, p[7], nn3);
            e0 = __builtin_amdgcn_exp2f(p[8] * c);
            e1 = __builtin_amdgcn_exp2f(p[9] * c);
            e2 = __builtin_amdgcn_exp2f(p[10] * c);
            e3 = __builtin_amdgcn_exp2f(p[11] * c);
            dd0 += e0; dd1 += e1; dd2 += e2; dd3 += e3;
            nn0 = fmaf(e0, p[8], nn0);  nn1 = fmaf(e1, p[9], nn1);
            nn2 = fmaf(e2, p[10], nn2); nn3 = fmaf(e3, p[11], nn3);
            e0 = __builtin_amdgcn_exp2f(p[12] * c);
            e1 = __builtin_amdgcn_exp2f(p[13] * c);
            e2 = __builtin_amdgcn_exp2f(p[14] * c);
            e3 = __builtin_amdgcn_exp2f(p[15] * c);
            dd0 += e0; dd1 += e1; dd2 += e2; dd3 += e3;
            nn0 = fmaf(e0, p[12], nn0); nn1 = fmaf(e1, p[13], nn1);
            nn2 = fmaf(e2, p[14], nn2); nn3 = fmaf(e3, p[15], nn3);

            float den = (dd0 + dd1) + (dd2 + dd3);
            float num = (nn0 + nn1) + (nn2 + nn3);
            den += __shfl_xor(den, 16); den += __shfl_xor(den, 32);
            num += __shfl_xor(num, 16); num += __shfl_xor(num, 32);
            sv = num * __builtin_amdgcn_rcpf(den);
            sn = sv * sv;
            sn += __shfl_xor(sn, 1); sn += __shfl_xor(sn, 2);
            sn += __shfl_xor(sn, 4); sn += __shfl_xor(sn, 8);
            factor = __builtin_amdgcn_sqrtf(sn)
                   * __builtin_amdgcn_rcpf(1.0f + sn);
            Vsum += sv * factor;
        }

        if (qB == 0)
            out[outbase + s * 128] = sv * factor;       // (1,O,B,DO), b=+8 per s

        // ---- T14 write-late: store next x-tile (transposed+swizzled) ----
        if (s < 3) {
            xw0[0] = xb0.x;  xw0[20] = xb0.y;  xw0[40] = xb0.z;  xw0[60] = xb0.w;
            xw1[0] = xb1.x;  xw1[20] = xb1.y;  xw1[40] = xb1.z;  xw1[60] = xb1.w;
            xw2[0] = xb2.x;  xw2[20] = xb2.y;  xw2[40] = xb2.z;  xw2[60] = xb2.w;
            xw3[0] = xb3.x;  xw3[20] = xb3.y;  xw3[40] = xb3.z;  xw3[60] = xb3.w;
        }
        __syncthreads();            // p-reads done & next x-tile ready
    }
}

extern "C" void kernel_launch(void* const* d_in, const int* in_sizes, int n_in,
                              void* d_out, int out_size, void* d_ws, size_t ws_size,
                              hipStream_t stream) {
    const float* x  = (const float*)d_in[0];
    const float* rw = (const float*)d_in[1];
    const float* ns = (const float*)d_in[2];
    float* out = (float*)d_out;
    (void)d_ws; (void)ws_size; (void)in_sizes; (void)n_in; (void)out_size;

    const int grid = 32 * 64;       // blockIdx = o*64 + bc
    routing_kernel<<<grid, THREADS, 73728, stream>>>(x, rw, ns, out);
}

// Round 12
// 83.076 us; speedup vs baseline: 1.1744x; 1.1744x over previous
//
#include <hip/hip_runtime.h>

// Capsule routing, MI355X. B=2048, I=64, O=32, DI=DO=16, 3 iters.
// R11 post-mortem: conflict count IDENTICAL (15.73M) under rotation change
// => ds_read_b128 issues in STRIDED-8 lane phases {p,p+8,...,p+56}. Within a
// phase, row-stride contributes 8*stride = 0 mod 8 quads, and a 16-float-row
// e-rotation spans only 4 quads -> inherent 2-way. (Model also explains R8's
// exact 2^20 = p-read 4-way.) R12 fix: skew the ROW BASE by one quad every
// 8 rows:  X(b,i,e) = b*1056 + 16*i + 4*(i>>3) + e   (floats)
// Read quad = (4i + (i>>3) + j) mod 8: across strided-8 lanes (i = p+8g),
// (i>>3) sweeps all 8 quads -> conflict-free. No e-rotation needed.
// Staging writes: bank = 4*(il>>1) + ih + C covers all 32 banks 2x -> free.
// Everything else identical to R11/R8 (verified):
// Block = 512 thr (8 waves), one o, 32 b in 4 sub-rounds of 8.
// LDS 66560 B dynamic: p 32 KB + x_t 33 KB -> 2 blocks/CU.
// A-phase: lane=i, wave w owns d-pair {2w,2w+1}; wq=32 regs; x via 4
//   ds_read_b128 per bb. B-phase: wave=bp, lane=(qB,dB); p[16] via 4 b128;
//   i-combine shfl_xor(16,32); squash-norm shfl_xor(1,2,4,8); 4-chain trees.
// T14 split staging; straight-line constant-indexed arrays (R7 lesson);
// builtin exp2/rcp/sqrt (|arg|<~95 no overflow); no min-wave forcing (R2/R5).

#define THREADS 512

__global__ __launch_bounds__(THREADS) void routing_kernel(
    const float* __restrict__ x,    // (B, DI, I) = (2048,16,64)
    const float* __restrict__ rw,   // (O, I, DO, DI) = (32,64,16,16)
    const float* __restrict__ ns,   // same
    float* __restrict__ out)        // (1, O, B, DO)
{
    extern __shared__ float lds[];  // [0,8192) p; [8192,16640) x_t (skewed)
    float* xlds = lds + 8192;       // X(b,i,e) = b*1056 + 16i + 4*(i>>3) + e

    const int tid  = threadIdx.x;
    const int w    = tid >> 6;      // wave 0..7
    const int lane = tid & 63;      // = i in A-phase

    const int o  = blockIdx.x >> 6;   // o-major: 64 consecutive blocks share W
    const int bc = blockIdx.x & 63;   // 32-b chunk
    const int bbase = bc * 32;

    // ---- W+noise fragment: lane=i, d in {2w, 2w+1} (32 VGPR) ----
    float wq0[16], wq1[16];
    {
        const int base = (o * 64 + lane) * 256 + w * 32;
        #pragma unroll
        for (int eq = 0; eq < 4; ++eq) {
            const float4 a0 = *reinterpret_cast<const float4*>(rw + base + eq * 4);
            const float4 n0 = *reinterpret_cast<const float4*>(ns + base + eq * 4);
            wq0[4*eq+0] = a0.x + n0.x;  wq0[4*eq+1] = a0.y + n0.y;
            wq0[4*eq+2] = a0.z + n0.z;  wq0[4*eq+3] = a0.w + n0.w;
            const float4 a1 = *reinterpret_cast<const float4*>(rw + base + 16 + eq * 4);
            const float4 n1 = *reinterpret_cast<const float4*>(ns + base + 16 + eq * 4);
            wq1[4*eq+0] = a1.x + n1.x;  wq1[4*eq+1] = a1.y + n1.y;
            wq1[4*eq+2] = a1.z + n1.z;  wq1[4*eq+3] = a1.w + n1.w;
        }
    }

    // ---- precomputed LDS addresses ----
    // p writes (A-phase), rows of 64, XOR-swizzled 16B slots
    const int d0 = 2 * w, d1 = 2 * w + 1;
    float* pw0 = lds + d0 * 64 + ((((lane >> 2) ^ (d0 & 7)) << 2) | (lane & 3));
    float* pw1 = lds + d1 * 64 + ((((lane >> 2) ^ (d1 & 7)) << 2) | (lane & 3));

    // p reads (B-phase)
    const int qB  = lane >> 4;      // i-quarter 0..3
    const int dB  = lane & 15;
    const int swz = dB & 7;
    const float4* prbase = reinterpret_cast<const float4*>(lds) + (w * 16 + dB) * 16;
    const float4* pr0 = prbase + ((4 * qB + 0) ^ swz);
    const float4* pr1 = prbase + ((4 * qB + 1) ^ swz);
    const float4* pr2 = prbase + ((4 * qB + 2) ^ swz);
    const float4* pr3 = prbase + ((4 * qB + 3) ^ swz);

    // x_t reads (A-phase): lane = i; base quad-skewed by i>>3
    const float* xrb = xlds + lane * 16 + ((lane >> 3) << 2);

    // x_t writes (staging): thread holds (b=w, e=4k+ih, i=4il+m)
    // addr = w*1056 + 64*il + 4*(il>>1) + 4k + ih + 16*m
    const int il = lane & 15, ih = lane >> 4;
    float* xwb = xlds + w * 1056 + il * 64 + ((il >> 1) << 2) + ih;
    float* xw0 = xwb + 0;
    float* xw1 = xwb + 4;
    float* xw2 = xwb + 8;
    float* xw3 = xwb + 12;

    const float4* xsrc0 = reinterpret_cast<const float4*>(x) + bbase * 256
                        + (w * 256 + lane);

    const int outbase = (o * 2048 + bbase + w) * 16 + dB;

    // ---- prologue: stage x-tile 0 (transposed+skewed) ----
    float4 xb0 = xsrc0[0];
    float4 xb1 = xsrc0[64];
    float4 xb2 = xsrc0[128];
    float4 xb3 = xsrc0[192];
    xw0[0] = xb0.x;  xw0[16] = xb0.y;  xw0[32] = xb0.z;  xw0[48] = xb0.w;
    xw1[0] = xb1.x;  xw1[16] = xb1.y;  xw1[32] = xb1.z;  xw1[48] = xb1.w;
    xw2[0] = xb2.x;  xw2[16] = xb2.y;  xw2[32] = xb2.z;  xw2[48] = xb2.w;
    xw3[0] = xb3.x;  xw3[16] = xb3.y;  xw3[32] = xb3.z;  xw3[48] = xb3.w;
    __syncthreads();                // x-tile 0 ready

    #pragma unroll
    for (int s = 0; s < 4; ++s) {
        // ---- A-phase: x_t -> p (8 b's, 4 conflict-free b128 reads each) ----
        #pragma unroll
        for (int bb = 0; bb < 8; ++bb) {
            const float4 v0 = *reinterpret_cast<const float4*>(xrb + bb * 1056 + 0);
            const float4 v1 = *reinterpret_cast<const float4*>(xrb + bb * 1056 + 4);
            const float4 v2 = *reinterpret_cast<const float4*>(xrb + bb * 1056 + 8);
            const float4 v3 = *reinterpret_cast<const float4*>(xrb + bb * 1056 + 12);
            float a0 = 0.f, a1 = 0.f;
            a0 = fmaf(wq0[0],  v0.x, a0);  a1 = fmaf(wq1[0],  v0.x, a1);
            a0 = fmaf(wq0[1],  v0.y, a0);  a1 = fmaf(wq1[1],  v0.y, a1);
            a0 = fmaf(wq0[2],  v0.z, a0);  a1 = fmaf(wq1[2],  v0.z, a1);
            a0 = fmaf(wq0[3],  v0.w, a0);  a1 = fmaf(wq1[3],  v0.w, a1);
            a0 = fmaf(wq0[4],  v1.x, a0);  a1 = fmaf(wq1[4],  v1.x, a1);
            a0 = fmaf(wq0[5],  v1.y, a0);  a1 = fmaf(wq1[5],  v1.y, a1);
            a0 = fmaf(wq0[6],  v1.z, a0);  a1 = fmaf(wq1[6],  v1.z, a1);
            a0 = fmaf(wq0[7],  v1.w, a0);  a1 = fmaf(wq1[7],  v1.w, a1);
            a0 = fmaf(wq0[8],  v2.x, a0);  a1 = fmaf(wq1[8],  v2.x, a1);
            a0 = fmaf(wq0[9],  v2.y, a0);  a1 = fmaf(wq1[9],  v2.y, a1);
            a0 = fmaf(wq0[10], v2.z, a0);  a1 = fmaf(wq1[10], v2.z, a1);
            a0 = fmaf(wq0[11], v2.w, a0);  a1 = fmaf(wq1[11], v2.w, a1);
            a0 = fmaf(wq0[12], v3.x, a0);  a1 = fmaf(wq1[12], v3.x, a1);
            a0 = fmaf(wq0[13], v3.y, a0);  a1 = fmaf(wq1[13], v3.y, a1);
            a0 = fmaf(wq0[14], v3.z, a0);  a1 = fmaf(wq1[14], v3.z, a1);
            a0 = fmaf(wq0[15], v3.w, a0);  a1 = fmaf(wq1[15], v3.w, a1);
            pw0[bb * 1024] = a0;
            pw1[bb * 1024] = a1;
        }
        __syncthreads();            // p ready; x_t free

        // ---- B-read: p[16] (i = qB*16 + 4jj + m) ----
        float p[16];
        {
            const float4 v0 = *pr0, v1 = *pr1, v2 = *pr2, v3 = *pr3;
            p[0]=v0.x; p[1]=v0.y; p[2]=v0.z; p[3]=v0.w;
            p[4]=v1.x; p[5]=v1.y; p[6]=v1.z; p[7]=v1.w;
            p[8]=v2.x; p[9]=v2.y; p[10]=v2.z; p[11]=v2.w;
            p[12]=v3.x; p[13]=v3.y; p[14]=v3.z; p[15]=v3.w;
        }

        // ---- T14 issue-early: next x-tile global loads ----
        if (s < 3) {
            const float4* xsrc = xsrc0 + (s + 1) * 2048;
            xb0 = xsrc[0];  xb1 = xsrc[64];  xb2 = xsrc[128];  xb3 = xsrc[192];
        }

        // ---- routing iterations ----
        float t0 = (p[0]+p[1]) + (p[2]+p[3]);
        float t1 = (p[4]+p[5]) + (p[6]+p[7]);
        float t2 = (p[8]+p[9]) + (p[10]+p[11]);
        float t3 = (p[12]+p[13]) + (p[14]+p[15]);
        float part = (t0 + t1) + (t2 + t3);
        part += __shfl_xor(part, 16);
        part += __shfl_xor(part, 32);
        float sv = part * (1.0f / 64.0f);

        float sn = sv * sv;         // squash norm over d (16-lane groups)
        sn += __shfl_xor(sn, 1); sn += __shfl_xor(sn, 2);
        sn += __shfl_xor(sn, 4); sn += __shfl_xor(sn, 8);
        float factor = __builtin_amdgcn_sqrtf(sn)
                     * __builtin_amdgcn_rcpf(1.0f + sn);
        float Vsum = sv * factor;

        #pragma unroll
        for (int it = 0; it < 2; ++it) {
            const float c = Vsum * 1.44269504089f;      // log2(e)
            float e0, e1, e2, e3;
            float dd0, dd1, dd2, dd3, nn0, nn1, nn2, nn3;
            e0 = __builtin_amdgcn_exp2f(p[0] * c);
            e1 = __builtin_amdgcn_exp2f(p[1] * c);
            e2 = __builtin_amdgcn_exp2f(p[2] * c);
            e3 = __builtin_amdgcn_exp2f(p[3] * c);
            dd0 = e0; dd1 = e1; dd2 = e2; dd3 = e3;
            nn0 = e0 * p[0]; nn1 = e1 * p[1]; nn2 = e2 * p[2]; nn3 = e3 * p[3];
            e0 = __builtin_amdgcn_exp2f(p[4] * c);
            e1 = __builtin_amdgcn_exp2f(p[5] * c);
            e2 = __builtin_amdgcn_exp2f(p[6] * c);
            e3 = __builtin_amdgcn_exp2f(p[7] * c);
            dd0 += e0; dd1 += e1; dd2 += e2; dd3 += e3;
            nn0 = fmaf(e0, p[4], nn0); nn1 = fmaf(e1, p[5], nn1);
            nn2 = fmaf(e2, p[6], nn2); nn3 = fmaf(e3, p[7], nn3);
            e0 = __builtin_amdgcn_exp2f(p[8] * c);
            e1 = __builtin_amdgcn_exp2f(p[9] * c);
            e2 = __builtin_amdgcn_exp2f(p[10] * c);
            e3 = __builtin_amdgcn_exp2f(p[11] * c);
            dd0 += e0; dd1 += e1; dd2 += e2; dd3 += e3;
            nn0 = fmaf(e0, p[8], nn0);  nn1 = fmaf(e1, p[9], nn1);
            nn2 = fmaf(e2, p[10], nn2); nn3 = fmaf(e3, p[11], nn3);
            e0 = __builtin_amdgcn_exp2f(p[12] * c);
            e1 = __builtin_amdgcn_exp2f(p[13] * c);
            e2 = __builtin_amdgcn_exp2f(p[14] * c);
            e3 = __builtin_amdgcn_exp2f(p[15] * c);
            dd0 += e0; dd1 += e1; dd2 += e2; dd3 += e3;
            nn0 = fmaf(e0, p[12], nn0); nn1 = fmaf(e1, p[13], nn1);
            nn2 = fmaf(e2, p[14], nn2); nn3 = fmaf(e3, p[15], nn3);

            float den = (dd0 + dd1) + (dd2 + dd3);
            float num = (nn0 + nn1) + (nn2 + nn3);
            den += __shfl_xor(den, 16); den += __shfl_xor(den, 32);
            num += __shfl_xor(num, 16); num += __shfl_xor(num, 32);
            sv = num * __builtin_amdgcn_rcpf(den);
            sn = sv * sv;
            sn += __shfl_xor(sn, 1); sn += __shfl_xor(sn, 2);
            sn += __shfl_xor(sn, 4); sn += __shfl_xor(sn, 8);
            factor = __builtin_amdgcn_sqrtf(sn)
                   * __builtin_amdgcn_rcpf(1.0f + sn);
            Vsum += sv * factor;
        }

        if (qB == 0)
            out[outbase + s * 128] = sv * factor;       // (1,O,B,DO), b=+8 per s

        // ---- T14 write-late: store next x-tile (transposed+skewed) ----
        if (s < 3) {
            xw0[0] = xb0.x;  xw0[16] = xb0.y;  xw0[32] = xb0.z;  xw0[48] = xb0.w;
            xw1[0] = xb1.x;  xw1[16] = xb1.y;  xw1[32] = xb1.z;  xw1[48] = xb1.w;
            xw2[0] = xb2.x;  xw2[16] = xb2.y;  xw2[32] = xb2.z;  xw2[48] = xb2.w;
            xw3[0] = xb3.x;  xw3[16] = xb3.y;  xw3[32] = xb3.z;  xw3[48] = xb3.w;
        }
        __syncthreads();            // p-reads done & next x-tile ready
    }
}

extern "C" void kernel_launch(void* const* d_in, const int* in_sizes, int n_in,
                              void* d_out, int out_size, void* d_ws, size_t ws_size,
                              hipStream_t stream) {
    const float* x  = (const float*)d_in[0];
    const float* rw = (const float*)d_in[1];
    const float* ns = (const float*)d_in[2];
    float* out = (float*)d_out;
    (void)d_ws; (void)ws_size; (void)in_sizes; (void)n_in; (void)out_size;

    const int grid = 32 * 64;       // blockIdx = o*64 + bc
    routing_kernel<<<grid, THREADS, 66560, stream>>>(x, rw, ns, out);
}